// Round 5
// baseline (406.623 us; speedup 1.0000x reference)
//
#include <hip/hip_runtime.h>
#include <math.h>

#define SEQL   2048
#define DIMM   1024
#define NST    16
#define INR    2048
#define TOKS   4096   // BATCH*SEQL
#define LCH    256    // scan chunk length
#define NCH    8      // chunks per sequence

typedef _Float16 f16;
typedef _Float16 f16x8 __attribute__((ext_vector_type(8)));
typedef float    f32x4 __attribute__((ext_vector_type(4)));

#define GLDS(SRC, DST) __builtin_amdgcn_global_load_lds( \
    (const __attribute__((address_space(1))) void*)(SRC), \
    (__attribute__((address_space(3))) void*)(DST), 16, 0, 0)

// ------------------------------------------------------------------
// W_x (33 x INR) -> W_xT (INR x 33)
__global__ __launch_bounds__(256) void k_wxt(const float* __restrict__ Wx,
                                             float* __restrict__ WxT)
{
    int i = blockIdx.x * 256 + threadIdx.x;
    if (i < 33 * INR) {
        int j = i / INR, ch = i % INR;
        WxT[ch * 33 + j] = Wx[i];
    }
}

// ------------------------------------------------------------------
// fp32 -> (hi fp16, lo fp16 scaled by 2048)
__global__ __launch_bounds__(256) void k_cvt_pair(const float* __restrict__ in,
        f16* __restrict__ hi, f16* __restrict__ lo, int n8)
{
    int i = blockIdx.x * 256 + threadIdx.x;
    if (i >= n8) return;
    const float4* p = (const float4*)(in + (size_t)i * 8);
    float4 a = p[0], b = p[1];
    float v[8] = {a.x, a.y, a.z, a.w, b.x, b.y, b.z, b.w};
    f16x8 H, L;
    #pragma unroll
    for (int j = 0; j < 8; ++j) {
        f16 h = (f16)v[j];
        float r = v[j] - (float)h;
        H[j] = h;
        L[j] = (f16)(r * 2048.f);
    }
    *(f16x8*)(hi + (size_t)i * 8) = H;
    *(f16x8*)(lo + (size_t)i * 8) = L;
}

// ------------------------------------------------------------------
// Split-fp16 MFMA GEMM (NT): C[M][N] = A[M][K]*B[N][K]^T, ~fp32 accuracy.
// Tile 128x128, BK=64, 4 waves (2x2), wave tile 64x64 = 4x4 frags.
// 3 MFMA per frag: hh->acc0; h*lo + lo*h -> acc1 (scaled 2^-11 at end).
// LDS: 4 planes x 16KB. Each 16-row x 32-f16 group (1KB) stored with a
// bank-conflict-free bijection slot(r,c)=((r+2c)&7)+8*((r>>3)+2c):
// any aligned 16/32-lane subset covers each bank-quad uniformly.
// Staged via global_load_lds (linear dest) with inverse-permuted per-lane
// global source; reads use slot() directly.  [conflict-free by design]
// epi=1: N-cols<INR -> out0 raw, else out1 silu. epi=0: partial K-split,
// dst = out0 + blockIdx.z*4Mi, Koff = blockIdx.z*Kloop.
__global__ __launch_bounds__(256, 2) void k_gemm2(
        const f16* __restrict__ Ah, const f16* __restrict__ Al,
        const f16* __restrict__ Bh, const f16* __restrict__ Bl,
        int Kloop, int Kstride, int epi, int Nst,
        float* __restrict__ out0, float* __restrict__ out1)
{
    __shared__ alignas(16) f16 SM[32768];   // 64 KB: planes @ 0/8192/16384/24576
    const int tid = threadIdx.x;
    const int l = tid & 63, w = tid >> 6;
    const int wm = (w >> 1) * 64;
    const int wn = (w & 1) * 64;
    const int m0 = blockIdx.y * 128, n0 = blockIdx.x * 128;
    const int koff = blockIdx.z * Kloop;

    // staging: wave w owns plane w (0 Ah, 1 Al, 2 Bh, 3 Bl)
    const f16* plsrc = (w == 0) ? Ah : (w == 1) ? Al : (w == 2) ? Bh : Bl;
    const int tr0 = (w < 2) ? m0 : n0;
    const int sc = l >> 4;                                        // chunk 0..3
    const int sr = ((l >> 3) & 1) * 8 + (((l & 7) - 2 * sc) & 7); // row 0..15

    // frag-read offset within a 512-elem group
    const int fr = l & 15, fc = l >> 4;
    const int foe = ((((fr + 2 * fc) & 7) + 8 * ((fr >> 3) + 2 * fc))) * 8;
    const int gA = wm >> 4, gB = wn >> 4;

    f32x4 acc0[4][4], acc1[4][4];
    #pragma unroll
    for (int mi = 0; mi < 4; ++mi)
        #pragma unroll
        for (int ni = 0; ni < 4; ++ni) {
            acc0[mi][ni] = (f32x4){0.f, 0.f, 0.f, 0.f};
            acc1[mi][ni] = (f32x4){0.f, 0.f, 0.f, 0.f};
        }

    for (int k0 = 0; k0 < Kloop; k0 += 64) {
        __syncthreads();
        #pragma unroll
        for (int i = 0; i < 8; ++i) {
            const size_t rbase =
                (size_t)(tr0 + i * 16 + sr) * Kstride + koff + k0 + sc * 8;
            GLDS(plsrc + rbase,      &SM[w * 8192 + (i * 2 + 0) * 512]);
            GLDS(plsrc + rbase + 32, &SM[w * 8192 + (i * 2 + 1) * 512]);
        }
        __syncthreads();
        #pragma unroll
        for (int hh = 0; hh < 2; ++hh) {
            f16x8 a_h[4], a_l[4], b_h[4], b_l[4];
            #pragma unroll
            for (int mi = 0; mi < 4; ++mi) {
                const int off = ((gA + mi) * 2 + hh) * 512 + foe;
                a_h[mi] = *(const f16x8*)&SM[off];
                a_l[mi] = *(const f16x8*)&SM[8192 + off];
            }
            #pragma unroll
            for (int ni = 0; ni < 4; ++ni) {
                const int off = ((gB + ni) * 2 + hh) * 512 + foe;
                b_h[ni] = *(const f16x8*)&SM[16384 + off];
                b_l[ni] = *(const f16x8*)&SM[24576 + off];
            }
            #pragma unroll
            for (int mi = 0; mi < 4; ++mi)
                #pragma unroll
                for (int ni = 0; ni < 4; ++ni) {
                    acc0[mi][ni] = __builtin_amdgcn_mfma_f32_16x16x32_f16(
                                       a_h[mi], b_h[ni], acc0[mi][ni], 0, 0, 0);
                    acc1[mi][ni] = __builtin_amdgcn_mfma_f32_16x16x32_f16(
                                       a_h[mi], b_l[ni], acc1[mi][ni], 0, 0, 0);
                    acc1[mi][ni] = __builtin_amdgcn_mfma_f32_16x16x32_f16(
                                       a_l[mi], b_h[ni], acc1[mi][ni], 0, 0, 0);
                }
        }
    }

    // epilogue: C/D layout col=lane&15, row=(lane>>4)*4+reg
    const int r0 = (l >> 4) * 4;
    float* dst0 = out0 + (epi ? 0 : (size_t)blockIdx.z * 4194304);
    #pragma unroll
    for (int mi = 0; mi < 4; ++mi)
        #pragma unroll
        for (int ni = 0; ni < 4; ++ni) {
            const int col = n0 + wn + ni * 16 + (l & 15);
            #pragma unroll
            for (int rr = 0; rr < 4; ++rr) {
                const int row = m0 + wm + mi * 16 + r0 + rr;
                float v = acc0[mi][ni][rr] + acc1[mi][ni][rr] * (1.0f / 2048.0f);
                if (epi) {
                    if (col < INR) {
                        out0[(size_t)row * INR + col] = v;
                    } else {
                        float s = v / (1.f + __expf(-v));
                        out1[(size_t)row * INR + (col - INR)] = s;
                    }
                } else {
                    dst0[(size_t)row * Nst + col] = v;
                }
            }
        }
}

// ------------------------------------------------------------------
// out = p0 + p1 (split-K reduce), over 1Mi float4
__global__ __launch_bounds__(256) void k_addout(const float* __restrict__ p,
                                                float* __restrict__ out)
{
    int i = blockIdx.x * 256 + threadIdx.x;
    float4 a = ((const float4*)p)[i];
    float4 b = ((const float4*)(p + 4194304))[i];
    float4 o = {a.x + b.x, a.y + b.y, a.z + b.z, a.w + b.w};
    ((float4*)out)[i] = o;
}

// ------------------------------------------------------------------
// Depthwise causal conv (K=4) + bias; u0 [tok][ch] -> uct [b][ch][t]
__global__ __launch_bounds__(256) void k_conv(const float* __restrict__ u0,
        const float* __restrict__ cw, const float* __restrict__ cb,
        float* __restrict__ uct)
{
    __shared__ float S[67][65];
    const int tid = threadIdx.x;
    const int ch0 = blockIdx.x * 64;
    const int t0  = blockIdx.y * 64;
    const int b   = blockIdx.z;
    const int ci  = tid & 63;
    for (int r = tid >> 6; r < 67; r += 4) {
        int t = t0 - 3 + r;
        S[r][ci] = (t < 0) ? 0.f : u0[((size_t)b*SEQL + t)*INR + ch0 + ci];
    }
    __syncthreads();
    const int ti = tid & 63;
    const int cq = tid >> 6;
    #pragma unroll
    for (int q = 0; q < 16; ++q) {
        int c  = cq + q*4;
        int ch = ch0 + c;
        float w0 = cw[ch*4+0], w1 = cw[ch*4+1], w2 = cw[ch*4+2], w3 = cw[ch*4+3];
        float acc = cb[ch]
            + w0*S[ti+0][c] + w1*S[ti+1][c] + w2*S[ti+2][c] + w3*S[ti+3][c];
        uct[((size_t)b*INR + ch)*SEQL + t0 + ti] = acc;
    }
}

// ------------------------------------------------------------------
// ssm = u @ W_x.T : reduce over channels, 16-way split -> partials.
__global__ __launch_bounds__(256) void k_ssm_part(const float* __restrict__ uct,
        const float* __restrict__ WxT, float* __restrict__ part)
{
    const int t  = blockIdx.x * 256 + threadIdx.x;
    const int cs = blockIdx.y;                      // 0..15
    const int b  = blockIdx.z;
    const int ch0 = cs * 128;
    float acc[33];
    #pragma unroll
    for (int j = 0; j < 33; ++j) acc[j] = 0.f;
    const float* up = uct + ((size_t)b*INR + ch0)*SEQL + t;
    for (int c = 0; c < 128; ++c) {
        float uv = up[(size_t)c * SEQL];
        const float* wr = WxT + (size_t)(ch0 + c) * 33;
        #pragma unroll
        for (int j = 0; j < 33; ++j) acc[j] = fmaf(uv, wr[j], acc[j]);
    }
    #pragma unroll
    for (int j = 0; j < 33; ++j)
        part[(((size_t)j*16 + cs)*2 + b)*SEQL + t] = acc[j];
}

__global__ __launch_bounds__(256) void k_ssm_reduce(const float* __restrict__ part,
        float* __restrict__ dtin, float* __restrict__ Bm, float* __restrict__ Cv)
{
    int g = blockIdx.x * 256 + threadIdx.x;
    if (g >= 33 * TOKS) return;
    int j = g / TOKS, m = g % TOKS;
    int b = m >> 11, t = m & 2047;
    float s = 0.f;
    #pragma unroll
    for (int cs = 0; cs < 16; ++cs)
        s += part[(((size_t)j*16 + cs)*2 + b)*SEQL + t];
    if (j < 16)      dtin[m*16 + j] = s;
    else if (j < 32) Bm[m*16 + (j-16)] = s;
    else             Cv[m] = s;
}

// ------------------------------------------------------------------
// delta = softplus(dt_in @ W_dt.T + b_dt) -> dT [b][ch][t]
__global__ __launch_bounds__(256) void k_delta(const float* __restrict__ dtin,
        const float* __restrict__ Wdt, const float* __restrict__ bdt,
        float* __restrict__ dT)
{
    __shared__ float Ds[16][68];
    __shared__ float Ws[16][68];
    const int tid = threadIdx.x;
    const int c0 = blockIdx.x * 64;
    const int m0 = blockIdx.y * 64;
    const int r = tid >> 2, kq = (tid & 3) * 4;
    {
        float4 dv = *(const float4*)&dtin[(size_t)(m0 + r)*16 + kq];
        float4 wv = *(const float4*)&Wdt [(size_t)(c0 + r)*16 + kq];
        Ds[kq+0][r]=dv.x; Ds[kq+1][r]=dv.y; Ds[kq+2][r]=dv.z; Ds[kq+3][r]=dv.w;
        Ws[kq+0][r]=wv.x; Ws[kq+1][r]=wv.y; Ws[kq+2][r]=wv.z; Ws[kq+3][r]=wv.w;
    }
    __syncthreads();
    const int tx = tid & 15, ty = tid >> 4;
    float acc[4][4];
    #pragma unroll
    for (int i = 0; i < 4; ++i)
        #pragma unroll
        for (int j = 0; j < 4; ++j) acc[i][j] = 0.f;
    #pragma unroll
    for (int kk = 0; kk < 16; ++kk) {
        float4 a4 = *(const float4*)&Ds[kk][ty*4];
        float4 b4 = *(const float4*)&Ws[kk][tx*4];
        float a[4] = {a4.x, a4.y, a4.z, a4.w};
        float wv[4] = {b4.x, b4.y, b4.z, b4.w};
        #pragma unroll
        for (int i = 0; i < 4; ++i)
            #pragma unroll
            for (int j = 0; j < 4; ++j)
                acc[i][j] = fmaf(a[i], wv[j], acc[i][j]);
    }
    const int b = m0 >> 11;
    const int tbase = (m0 & 2047) + ty*4;
    #pragma unroll
    for (int j = 0; j < 4; ++j) {
        int ch = c0 + tx*4 + j;
        float bias = bdt[ch];
        float4 o;
        o.x = log1pf(__expf(acc[0][j] + bias));
        o.y = log1pf(__expf(acc[1][j] + bias));
        o.z = log1pf(__expf(acc[2][j] + bias));
        o.w = log1pf(__expf(acc[3][j] + bias));
        *(float4*)&dT[((size_t)b*INR + ch)*SEQL + tbase] = o;
    }
}

// ------------------------------------------------------------------
// Chunked scan, pass 1: per-chunk local scan -> h_out, E = exp(A*sum(d)).
__global__ __launch_bounds__(256) void k_scan1(const float* __restrict__ dT,
        const float* __restrict__ uct, const float* __restrict__ Bm,
        const float* __restrict__ Alog,
        float* __restrict__ hout, float* __restrict__ Eag)
{
    __shared__ float dS[16][68];
    __shared__ float uS[16][68];
    __shared__ float bT[16][68];   // B transposed: [s][t]
    const int tid = threadIdx.x;
    const int g = tid >> 4, s = tid & 15;
    const int ch0 = blockIdx.x * 16;
    const int c   = blockIdx.y;
    const int b   = blockIdx.z;
    const int ch  = ch0 + g;
    const int tbase = c * LCH;
    const size_t mb = (size_t)b * SEQL;
    const float A = -__expf(Alog[ch*NST + s]);
    float h = 0.f, Dsum = 0.f;
    const int row = tid >> 4, col4 = (tid & 15) * 4;
    const int sB = tid & 15, tq = tid >> 4;
    const float* dRow = dT  + ((size_t)b*INR + ch0 + row)*SEQL + tbase;
    const float* uRow = uct + ((size_t)b*INR + ch0 + row)*SEQL + tbase;

    for (int t0 = 0; t0 < LCH; t0 += 64) {
        __syncthreads();
        *(float4*)&dS[row][col4] = *(const float4*)&dRow[t0 + col4];
        *(float4*)&uS[row][col4] = *(const float4*)&uRow[t0 + col4];
        #pragma unroll
        for (int k = 0; k < 4; ++k)
            bT[sB][tq*4 + k] = Bm[(mb + tbase + t0 + tq*4 + k)*16 + sB];
        __syncthreads();
        #pragma unroll
        for (int q = 0; q < 16; ++q) {
            float4 d4 = *(const float4*)&dS[g][q*4];
            float4 u4 = *(const float4*)&uS[g][q*4];
            float4 b4 = *(const float4*)&bT[s][q*4];
            h = fmaf(h, __expf(d4.x*A), u4.x*b4.x);
            h = fmaf(h, __expf(d4.y*A), u4.y*b4.y);
            h = fmaf(h, __expf(d4.z*A), u4.z*b4.z);
            h = fmaf(h, __expf(d4.w*A), u4.w*b4.w);
            Dsum += (d4.x + d4.y) + (d4.z + d4.w);
        }
    }
    size_t idx = (((size_t)(b*NCH + c))*INR + ch)*NST + s;
    hout[idx] = h;
    Eag[idx]  = __expf(A * Dsum);
}

// ------------------------------------------------------------------
// Chunked scan, pass 2: serial combine (hin aliases hout, in-place).
__global__ __launch_bounds__(256) void k_scan2(const float* __restrict__ hout,
        const float* __restrict__ Eag, float* __restrict__ hin)
{
    int p = blockIdx.x * 256 + threadIdx.x;   // over 2*INR*NST
    if (p >= 2 * INR * NST) return;
    int b = p >> 15;
    int r = p & 32767;
    float h = 0.f;
    for (int c = 0; c < NCH; ++c) {
        size_t idx = ((size_t)(b*NCH + c)) * (INR*NST) + r;
        float E  = Eag[idx];
        float ho = hout[idx];
        hin[idx] = h;
        h = h * E + ho;
    }
}

// ------------------------------------------------------------------
// Chunked scan, pass 3: local scan seeded with h_in; deferred 16-state
// reduction via LDS every 16 steps; epilogue fuses y*sres -> hi/lo f16
// planes for the output GEMM (replaces the old cvt_mul kernel).
__global__ __launch_bounds__(256) void k_scan3(const float* __restrict__ dT,
        const float* __restrict__ uct, const float* __restrict__ Bm,
        const float* __restrict__ Cv, const float* __restrict__ Alog,
        const float* __restrict__ hin, const float* __restrict__ sres,
        f16* __restrict__ AoH, f16* __restrict__ AoL)
{
    __shared__ float dS[16][68];
    __shared__ float uS[16][68];
    __shared__ float bT[16][68];
    __shared__ float cS[64];
    __shared__ float hS[16*272];   // [step][g*17+s]
    const int tid = threadIdx.x;
    const int g = tid >> 4, s = tid & 15;
    const int ch0 = blockIdx.x * 16;
    const int c   = blockIdx.y;
    const int b   = blockIdx.z;
    const int ch  = ch0 + g;
    const int tbase = c * LCH;
    const size_t mb = (size_t)b * SEQL;
    const float A = -__expf(Alog[ch*NST + s]);
    float h = hin[(((size_t)(b*NCH + c))*INR + ch)*NST + s];
    const int row = tid >> 4, col4 = (tid & 15) * 4;
    const int sB = tid & 15, tq = tid >> 4;
    const int ci = tid & 15, tw = tid >> 4;   // reduce-phase roles
    const float* dRow = dT  + ((size_t)b*INR + ch0 + row)*SEQL + tbase;
    const float* uRow = uct + ((size_t)b*INR + ch0 + row)*SEQL + tbase;

    for (int t0 = 0; t0 < LCH; t0 += 64) {
        __syncthreads();
        *(float4*)&dS[row][col4] = *(const float4*)&dRow[t0 + col4];
        *(float4*)&uS[row][col4] = *(const float4*)&uRow[t0 + col4];
        #pragma unroll
        for (int k = 0; k < 4; ++k)
            bT[sB][tq*4 + k] = Bm[(mb + tbase + t0 + tq*4 + k)*16 + sB];
        if (tid < 64) cS[tid] = Cv[mb + tbase + t0 + tid];
        __syncthreads();
        #pragma unroll
        for (int sub = 0; sub < 4; ++sub) {
            #pragma unroll
            for (int q = 0; q < 4; ++q) {
                float4 d4 = *(const float4*)&dS[g][sub*16 + q*4];
                float4 u4 = *(const float4*)&uS[g][sub*16 + q*4];
                float4 b4 = *(const float4*)&bT[s][sub*16 + q*4];
                h = fmaf(h, __expf(d4.x*A), u4.x*b4.x);
                hS[(q*4+0)*272 + g*17 + s] = h;
                h = fmaf(h, __expf(d4.y*A), u4.y*b4.y);
                hS[(q*4+1)*272 + g*17 + s] = h;
                h = fmaf(h, __expf(d4.z*A), u4.z*b4.z);
                hS[(q*4+2)*272 + g*17 + s] = h;
                h = fmaf(h, __expf(d4.w*A), u4.w*b4.w);
                hS[(q*4+3)*272 + g*17 + s] = h;
            }
            __syncthreads();
            float v = 0.f;
            #pragma unroll
            for (int ss = 0; ss < 16; ++ss)
                v += hS[tw*272 + ci*17 + ss];
            const int tl = sub*16 + tw;     // tile-local token 0..63
            const size_t gi = (mb + tbase + t0 + tl)*INR + ch0 + ci;
            float pv = (v * cS[tl]) * sres[gi];
            f16 hh = (f16)pv;
            AoH[gi] = hh;
            AoL[gi] = (f16)((pv - (float)hh) * 2048.f);
            __syncthreads();
        }
    }
}

// ------------------------------------------------------------------
extern "C" void kernel_launch(void* const* d_in, const int* in_sizes, int n_in,
                              void* d_out, int out_size, void* d_ws, size_t ws_size,
                              hipStream_t stream)
{
    (void)in_sizes; (void)n_in; (void)out_size; (void)ws_size;
    const float* x     = (const float*)d_in[0];
    const float* W_in  = (const float*)d_in[1];
    const float* cw    = (const float*)d_in[2];
    const float* cb    = (const float*)d_in[3];
    const float* W_x   = (const float*)d_in[4];
    const float* W_dt  = (const float*)d_in[5];
    const float* b_dt  = (const float*)d_in[6];
    const float* W_out = (const float*)d_in[7];
    const float* A_log = (const float*)d_in[8];
    float* out = (float*)d_out;

    float* ws = (float*)d_ws;
    const size_t MI = 1024 * 1024;
    float* u0   = ws;                 // [0,8Mi)   u0 -> dT
    float* sres = ws + 8*MI;          // [8,16Mi)  sres -> gemmout partials
    float* uct  = ws + 16*MI;         // [16,24Mi)
    float* part = ws + 24*MI;         // [24,~26.1Mi) ssm partials (dead early)
    float* dtin = ws + 32*MI;         // 64Ki
    float* Bm   = dtin + 65536;       // 64Ki
    float* Cv   = Bm + 65536;         // 4Ki
    float* WxT  = Cv + 4096;          // 66Ki
    float* dT   = u0;
    // chunk-scan aggregates live in d_out (dead until addout): 1Mi floats
    float* houtb = out;               // 512Ki floats (hout, then hin in-place)
    float* Eag   = out + 524288;      // 512Ki floats
    // f16 planes, phase 1 (gemm1 inputs) — over [16,24Mi), dead after gemm1
    f16* Xhi = (f16*)(ws + 16*MI);
    f16* Xlo = (f16*)(ws + 18*MI);
    f16* Whi = (f16*)(ws + 20*MI);
    f16* Wlo = (f16*)(ws + 22*MI);
    // f16 planes, phase 2 (gemmout inputs)
    f16* AoH = (f16*)(ws + 24*MI);    // [24,26Mi) (after part is dead)
    f16* AoL = (f16*)(ws + 26*MI);    // [26,28Mi)
    f16* WoH = (f16*)(ws + 16*MI);    // [16,17Mi) (after uct is dead)
    f16* WoL = (f16*)(ws + 17*MI);    // [17,18Mi)
    float* pK = sres;                 // split-K partials: [8,12Mi) + [12,16Mi)

    k_wxt      <<<dim3((33*INR + 255)/256), 256, 0, stream>>>(W_x, WxT);
    k_cvt_pair <<<dim3(2048), 256, 0, stream>>>(x,    Xhi, Xlo, 524288);
    k_cvt_pair <<<dim3(2048), 256, 0, stream>>>(W_in, Whi, Wlo, 524288);
    k_gemm2    <<<dim3(32, 32), 256, 0, stream>>>(Xhi, Xlo, Whi, Wlo,
                                                  DIMM, DIMM, 1, INR, u0, sres);
    k_conv     <<<dim3(32, 32, 2), 256, 0, stream>>>(u0, cw, cb, uct);
    k_ssm_part <<<dim3(8, 16, 2), 256, 0, stream>>>(uct, WxT, part);
    k_ssm_reduce<<<dim3((33*TOKS + 255)/256), 256, 0, stream>>>(part, dtin, Bm, Cv);
    k_delta    <<<dim3(32, 64), 256, 0, stream>>>(dtin, W_dt, b_dt, dT);
    k_scan1    <<<dim3(128, NCH, 2), 256, 0, stream>>>(dT, uct, Bm, A_log, houtb, Eag);
    k_scan2    <<<dim3(256), 256, 0, stream>>>(houtb, Eag, houtb);
    k_scan3    <<<dim3(128, NCH, 2), 256, 0, stream>>>(dT, uct, Bm, Cv, A_log,
                                                       houtb, sres, AoH, AoL);
    k_cvt_pair <<<dim3(1024), 256, 0, stream>>>(W_out, WoH, WoL, 262144);
    k_gemm2    <<<dim3(8, 32, 2), 256, 0, stream>>>(AoH, AoL, WoH, WoL,
                                                    DIMM, INR, 0, DIMM, pK, nullptr);
    k_addout   <<<dim3(4096), 256, 0, stream>>>(pK, out);
}

// Round 7
// 390.760 us; speedup vs baseline: 1.0406x; 1.0406x over previous
//
#include <hip/hip_runtime.h>
#include <math.h>

#define SEQL   2048
#define DIMM   1024
#define NST    16
#define INR    2048
#define TOKS   4096   // BATCH*SEQL
#define LCH    256    // scan chunk length
#define NCH    8      // chunks per sequence

typedef _Float16 f16;
typedef _Float16 f16x8 __attribute__((ext_vector_type(8)));
typedef float    f32x4 __attribute__((ext_vector_type(4)));

__device__ __forceinline__ int swz(int r) { return (r & 3) ^ ((r >> 2) & 3); }

#define GLDS(SRC, DST) __builtin_amdgcn_global_load_lds( \
    (const __attribute__((address_space(1))) void*)(SRC), \
    (__attribute__((address_space(3))) void*)(DST), 16, 0, 0)

// ------------------------------------------------------------------
// fp32 -> (hi fp16, lo fp16 scaled by 2048)
__device__ __forceinline__ void cvt8(const float* __restrict__ in, int i,
                                     f16* __restrict__ hi, f16* __restrict__ lo)
{
    const float4* p = (const float4*)(in + (size_t)i * 8);
    float4 a = p[0], b = p[1];
    float v[8] = {a.x, a.y, a.z, a.w, b.x, b.y, b.z, b.w};
    f16x8 H, L;
    #pragma unroll
    for (int j = 0; j < 8; ++j) {
        f16 h = (f16)v[j];
        float r = v[j] - (float)h;
        H[j] = h;
        L[j] = (f16)(r * 2048.f);
    }
    *(f16x8*)(hi + (size_t)i * 8) = H;
    *(f16x8*)(lo + (size_t)i * 8) = L;
}

// Fused prep: W_x transpose + split conversion of x and W_in.
// (W_out is converted AFTER scan3, into the then-dead uct region.)
__global__ __launch_bounds__(256) void k_prep(
        const float* __restrict__ Wx,   float* __restrict__ WxT,
        const float* __restrict__ x,    f16* __restrict__ Xhi, f16* __restrict__ Xlo,
        const float* __restrict__ Win,  f16* __restrict__ Whi, f16* __restrict__ Wlo)
{
    const int b = blockIdx.x, tid = threadIdx.x;
    if (b < 264) {                       // W_x transpose: 33*INR elems
        int i = b * 256 + tid;
        int j = i / INR, ch = i % INR;
        WxT[ch * 33 + j] = Wx[i];
    } else if (b < 264 + 2048) {         // x: 4Mi floats
        cvt8(x, (b - 264) * 256 + tid, Xhi, Xlo);
    } else {                             // W_in: 4Mi floats
        cvt8(Win, (b - 264 - 2048) * 256 + tid, Whi, Wlo);
    }
}

__global__ __launch_bounds__(256) void k_cvt_pair(const float* __restrict__ in,
        f16* __restrict__ hi, f16* __restrict__ lo, int n8)
{
    int i = blockIdx.x * 256 + threadIdx.x;
    if (i < n8) cvt8(in, i, hi, lo);
}

// ------------------------------------------------------------------
// Split-fp16 MFMA GEMM (NT): C[M][N] = A[M][K]*B[N][K]^T, ~fp32 accuracy.
// Tile 128(m) x 64(n), BK=32, 4 waves (2x2), wave tile 64x32 = 4x2 frags.
// 3 MFMA per frag pair: hh -> acc0 ; hl + lh -> acc1 (scaled 2^-11 at end).
// 24 KB LDS -> high occupancy (beat a 128x128/BK64 variant by 14%: 64KB LDS
// halves blocks/CU; ds_read_b128 conflict counter sits at its inherent
// 16-cyc/read floor for all layouts tried, so reads are not the lever).
// epi=1: N=4096 logical; col<INR -> out0 raw, col>=INR -> out1 = silu.
// epi=0: split-K partial; Koff = blockIdx.z*Kloop, dst += z*4Mi floats.
__global__ __launch_bounds__(256, 3) void k_gemm_split(
        const f16* __restrict__ Ah, const f16* __restrict__ Al,
        const f16* __restrict__ Bh, const f16* __restrict__ Bl,
        int Kloop, int Kstride, int epi, int Nst,
        float* __restrict__ out0, float* __restrict__ out1)
{
    const int AHI = 0, ALO = 4096, BHI = 8192, BLO = 10240;
    __shared__ alignas(16) f16 SM[12288];   // 24 KB

    const int tid = threadIdx.x;
    const int l   = tid & 63;
    const int w   = tid >> 6;
    const int wm  = (w >> 1) * 64;
    const int wn  = (w & 1) * 32;
    const int lr  = l & 15;
    const int kg  = l >> 4;
    const int m0  = blockIdx.y * 128;
    const int n0  = blockIdx.x * 64;
    const int koff = blockIdx.z * Kloop;

    const int srow = l >> 2;
    const int sc   = (l & 3) ^ swz(srow);
    const int w16  = w * 16;
    const int fo   = lr * 32 + (kg ^ swz(lr)) * 8;

    f32x4 acc0[4][2], acc1[4][2];
    #pragma unroll
    for (int mi = 0; mi < 4; ++mi)
        #pragma unroll
        for (int ni = 0; ni < 2; ++ni) {
            acc0[mi][ni] = (f32x4){0.f, 0.f, 0.f, 0.f};
            acc1[mi][ni] = (f32x4){0.f, 0.f, 0.f, 0.f};
        }

    for (int k0 = 0; k0 < Kloop; k0 += 32) {
        __syncthreads();
        #pragma unroll
        for (int q = 0; q < 2; ++q) {
            const int rl = q * 64 + w16 + srow;
            const size_t go = (size_t)(m0 + rl) * Kstride + koff + k0 + sc * 8;
            GLDS(Ah + go, &SM[AHI + (q * 64 + w16) * 32]);
            GLDS(Al + go, &SM[ALO + (q * 64 + w16) * 32]);
        }
        {
            const int rl = w16 + srow;
            const size_t go = (size_t)(n0 + rl) * Kstride + koff + k0 + sc * 8;
            GLDS(Bh + go, &SM[BHI + w16 * 32]);
            GLDS(Bl + go, &SM[BLO + w16 * 32]);
        }
        __syncthreads();

        f16x8 ah[4], al4[4], bh[2], bl[2];
        #pragma unroll
        for (int mi = 0; mi < 4; ++mi) {
            int off = (wm + mi * 16) * 32 + fo;
            ah[mi]  = *(const f16x8*)&SM[AHI + off];
            al4[mi] = *(const f16x8*)&SM[ALO + off];
        }
        #pragma unroll
        for (int ni = 0; ni < 2; ++ni) {
            int off = (wn + ni * 16) * 32 + fo;
            bh[ni] = *(const f16x8*)&SM[BHI + off];
            bl[ni] = *(const f16x8*)&SM[BLO + off];
        }
        #pragma unroll
        for (int mi = 0; mi < 4; ++mi)
            #pragma unroll
            for (int ni = 0; ni < 2; ++ni) {
                acc0[mi][ni] = __builtin_amdgcn_mfma_f32_16x16x32_f16(
                                   ah[mi], bh[ni], acc0[mi][ni], 0, 0, 0);
                acc1[mi][ni] = __builtin_amdgcn_mfma_f32_16x16x32_f16(
                                   ah[mi], bl[ni], acc1[mi][ni], 0, 0, 0);
                acc1[mi][ni] = __builtin_amdgcn_mfma_f32_16x16x32_f16(
                                   al4[mi], bh[ni], acc1[mi][ni], 0, 0, 0);
            }
    }

    // epilogue: C/D layout col=lane&15, row=(lane>>4)*4+reg
    const int r0 = (l >> 4) * 4;
    float* dst0 = out0 + (epi ? 0 : (size_t)blockIdx.z * 4194304);
    #pragma unroll
    for (int mi = 0; mi < 4; ++mi)
        #pragma unroll
        for (int ni = 0; ni < 2; ++ni) {
            const int col = n0 + wn + ni * 16 + (l & 15);
            #pragma unroll
            for (int rr = 0; rr < 4; ++rr) {
                const int row = m0 + wm + mi * 16 + r0 + rr;
                float v = acc0[mi][ni][rr] + acc1[mi][ni][rr] * (1.0f / 2048.0f);
                if (epi) {
                    if (col < INR) {
                        out0[(size_t)row * INR + col] = v;
                    } else {
                        float s = v / (1.f + __expf(-v));
                        out1[(size_t)row * INR + (col - INR)] = s;
                    }
                } else {
                    dst0[(size_t)row * Nst + col] = v;
                }
            }
        }
}

// ------------------------------------------------------------------
// out = p0 + p1 (split-K reduce), over 1Mi float4
__global__ __launch_bounds__(256) void k_addout(const float* __restrict__ p,
                                                float* __restrict__ out)
{
    int i = blockIdx.x * 256 + threadIdx.x;
    float4 a = ((const float4*)p)[i];
    float4 b = ((const float4*)(p + 4194304))[i];
    float4 o = {a.x + b.x, a.y + b.y, a.z + b.z, a.w + b.w};
    ((float4*)out)[i] = o;
}

// ------------------------------------------------------------------
// Depthwise causal conv (K=4) + bias; u0 [tok][ch] -> uct [b][ch][t]
__global__ __launch_bounds__(256) void k_conv(const float* __restrict__ u0,
        const float* __restrict__ cw, const float* __restrict__ cb,
        float* __restrict__ uct)
{
    __shared__ float S[67][65];
    const int tid = threadIdx.x;
    const int ch0 = blockIdx.x * 64;
    const int t0  = blockIdx.y * 64;
    const int b   = blockIdx.z;
    const int ci  = tid & 63;
    for (int r = tid >> 6; r < 67; r += 4) {
        int t = t0 - 3 + r;
        S[r][ci] = (t < 0) ? 0.f : u0[((size_t)b*SEQL + t)*INR + ch0 + ci];
    }
    __syncthreads();
    const int ti = tid & 63;
    const int cq = tid >> 6;
    #pragma unroll
    for (int q = 0; q < 16; ++q) {
        int c  = cq + q*4;
        int ch = ch0 + c;
        float w0 = cw[ch*4+0], w1 = cw[ch*4+1], w2 = cw[ch*4+2], w3 = cw[ch*4+3];
        float acc = cb[ch]
            + w0*S[ti+0][c] + w1*S[ti+1][c] + w2*S[ti+2][c] + w3*S[ti+3][c];
        uct[((size_t)b*INR + ch)*SEQL + t0 + ti] = acc;
    }
}

// ------------------------------------------------------------------
// ssm = u @ W_x.T : reduce over channels, 16-way split -> partials.
__global__ __launch_bounds__(256) void k_ssm_part(const float* __restrict__ uct,
        const float* __restrict__ WxT, float* __restrict__ part)
{
    const int t  = blockIdx.x * 256 + threadIdx.x;
    const int cs = blockIdx.y;                      // 0..15
    const int b  = blockIdx.z;
    const int ch0 = cs * 128;
    float acc[33];
    #pragma unroll
    for (int j = 0; j < 33; ++j) acc[j] = 0.f;
    const float* up = uct + ((size_t)b*INR + ch0)*SEQL + t;
    for (int c = 0; c < 128; ++c) {
        float uv = up[(size_t)c * SEQL];
        const float* wr = WxT + (size_t)(ch0 + c) * 33;
        #pragma unroll
        for (int j = 0; j < 33; ++j) acc[j] = fmaf(uv, wr[j], acc[j]);
    }
    #pragma unroll
    for (int j = 0; j < 33; ++j)
        part[(((size_t)j*16 + cs)*2 + b)*SEQL + t] = acc[j];
}

__global__ __launch_bounds__(256) void k_ssm_reduce(const float* __restrict__ part,
        float* __restrict__ dtin, float* __restrict__ Bm, float* __restrict__ Cv)
{
    int g = blockIdx.x * 256 + threadIdx.x;
    if (g >= 33 * TOKS) return;
    int j = g / TOKS, m = g % TOKS;
    int b = m >> 11, t = m & 2047;
    float s = 0.f;
    #pragma unroll
    for (int cs = 0; cs < 16; ++cs)
        s += part[(((size_t)j*16 + cs)*2 + b)*SEQL + t];
    if (j < 16)      dtin[m*16 + j] = s;
    else if (j < 32) Bm[m*16 + (j-16)] = s;
    else             Cv[m] = s;
}

// ------------------------------------------------------------------
// delta = softplus(dt_in @ W_dt.T + b_dt) -> dT [b][ch][t]
__global__ __launch_bounds__(256) void k_delta(const float* __restrict__ dtin,
        const float* __restrict__ Wdt, const float* __restrict__ bdt,
        float* __restrict__ dT)
{
    __shared__ float Ds[16][68];
    __shared__ float Ws[16][68];
    const int tid = threadIdx.x;
    const int c0 = blockIdx.x * 64;
    const int m0 = blockIdx.y * 64;
    const int r = tid >> 2, kq = (tid & 3) * 4;
    {
        float4 dv = *(const float4*)&dtin[(size_t)(m0 + r)*16 + kq];
        float4 wv = *(const float4*)&Wdt [(size_t)(c0 + r)*16 + kq];
        Ds[kq+0][r]=dv.x; Ds[kq+1][r]=dv.y; Ds[kq+2][r]=dv.z; Ds[kq+3][r]=dv.w;
        Ws[kq+0][r]=wv.x; Ws[kq+1][r]=wv.y; Ws[kq+2][r]=wv.z; Ws[kq+3][r]=wv.w;
    }
    __syncthreads();
    const int tx = tid & 15, ty = tid >> 4;
    float acc[4][4];
    #pragma unroll
    for (int i = 0; i < 4; ++i)
        #pragma unroll
        for (int j = 0; j < 4; ++j) acc[i][j] = 0.f;
    #pragma unroll
    for (int kk = 0; kk < 16; ++kk) {
        float4 a4 = *(const float4*)&Ds[kk][ty*4];
        float4 b4 = *(const float4*)&Ws[kk][tx*4];
        float a[4] = {a4.x, a4.y, a4.z, a4.w};
        float wv[4] = {b4.x, b4.y, b4.z, b4.w};
        #pragma unroll
        for (int i = 0; i < 4; ++i)
            #pragma unroll
            for (int j = 0; j < 4; ++j)
                acc[i][j] = fmaf(a[i], wv[j], acc[i][j]);
    }
    const int b = m0 >> 11;
    const int tbase = (m0 & 2047) + ty*4;
    #pragma unroll
    for (int j = 0; j < 4; ++j) {
        int ch = c0 + tx*4 + j;
        float bias = bdt[ch];
        float4 o;
        o.x = log1pf(__expf(acc[0][j] + bias));
        o.y = log1pf(__expf(acc[1][j] + bias));
        o.z = log1pf(__expf(acc[2][j] + bias));
        o.w = log1pf(__expf(acc[3][j] + bias));
        *(float4*)&dT[((size_t)b*INR + ch)*SEQL + tbase] = o;
    }
}

// ------------------------------------------------------------------
// Chunked scan, pass 1: per-chunk local scan -> h_out, E = exp(A*sum(d)).
__global__ __launch_bounds__(256) void k_scan1(const float* __restrict__ dT,
        const float* __restrict__ uct, const float* __restrict__ Bm,
        const float* __restrict__ Alog,
        float* __restrict__ hout, float* __restrict__ Eag)
{
    __shared__ float dS[16][68];
    __shared__ float uS[16][68];
    __shared__ float bT[16][68];   // B transposed: [s][t]
    const int tid = threadIdx.x;
    const int g = tid >> 4, s = tid & 15;
    const int ch0 = blockIdx.x * 16;
    const int c   = blockIdx.y;
    const int b   = blockIdx.z;
    const int ch  = ch0 + g;
    const int tbase = c * LCH;
    const size_t mb = (size_t)b * SEQL;
    const float A = -__expf(Alog[ch*NST + s]);
    float h = 0.f, Dsum = 0.f;
    const int row = tid >> 4, col4 = (tid & 15) * 4;
    const int sB = tid & 15, tq = tid >> 4;
    const float* dRow = dT  + ((size_t)b*INR + ch0 + row)*SEQL + tbase;
    const float* uRow = uct + ((size_t)b*INR + ch0 + row)*SEQL + tbase;

    for (int t0 = 0; t0 < LCH; t0 += 64) {
        __syncthreads();
        *(float4*)&dS[row][col4] = *(const float4*)&dRow[t0 + col4];
        *(float4*)&uS[row][col4] = *(const float4*)&uRow[t0 + col4];
        #pragma unroll
        for (int k = 0; k < 4; ++k)
            bT[sB][tq*4 + k] = Bm[(mb + tbase + t0 + tq*4 + k)*16 + sB];
        __syncthreads();
        #pragma unroll
        for (int q = 0; q < 16; ++q) {
            float4 d4 = *(const float4*)&dS[g][q*4];
            float4 u4 = *(const float4*)&uS[g][q*4];
            float4 b4 = *(const float4*)&bT[s][q*4];
            h = fmaf(h, __expf(d4.x*A), u4.x*b4.x);
            h = fmaf(h, __expf(d4.y*A), u4.y*b4.y);
            h = fmaf(h, __expf(d4.z*A), u4.z*b4.z);
            h = fmaf(h, __expf(d4.w*A), u4.w*b4.w);
            Dsum += (d4.x + d4.y) + (d4.z + d4.w);
        }
    }
    size_t idx = (((size_t)(b*NCH + c))*INR + ch)*NST + s;
    hout[idx] = h;
    Eag[idx]  = __expf(A * Dsum);
}

// ------------------------------------------------------------------
// Chunked scan, pass 2: serial combine (hin aliases hout, in-place).
__global__ __launch_bounds__(256) void k_scan2(const float* __restrict__ hout,
        const float* __restrict__ Eag, float* __restrict__ hin)
{
    int p = blockIdx.x * 256 + threadIdx.x;   // over 2*INR*NST
    if (p >= 2 * INR * NST) return;
    int b = p >> 15;
    int r = p & 32767;
    float h = 0.f;
    for (int c = 0; c < NCH; ++c) {
        size_t idx = ((size_t)(b*NCH + c)) * (INR*NST) + r;
        float E  = Eag[idx];
        float ho = hout[idx];
        hin[idx] = h;
        h = h * E + ho;
    }
}

// ------------------------------------------------------------------
// Chunked scan, pass 3: local scan seeded with h_in; deferred 16-state
// reduction via LDS every 16 steps; epilogue fuses y*sres -> hi/lo f16
// planes for the output GEMM.
__global__ __launch_bounds__(256) void k_scan3(const float* __restrict__ dT,
        const float* __restrict__ uct, const float* __restrict__ Bm,
        const float* __restrict__ Cv, const float* __restrict__ Alog,
        const float* __restrict__ hin, const float* __restrict__ sres,
        f16* __restrict__ AoH, f16* __restrict__ AoL)
{
    __shared__ float dS[16][68];
    __shared__ float uS[16][68];
    __shared__ float bT[16][68];
    __shared__ float cS[64];
    __shared__ float hS[16*272];   // [step][g*17+s]
    const int tid = threadIdx.x;
    const int g = tid >> 4, s = tid & 15;
    const int ch0 = blockIdx.x * 16;
    const int c   = blockIdx.y;
    const int b   = blockIdx.z;
    const int ch  = ch0 + g;
    const int tbase = c * LCH;
    const size_t mb = (size_t)b * SEQL;
    const float A = -__expf(Alog[ch*NST + s]);
    float h = hin[(((size_t)(b*NCH + c))*INR + ch)*NST + s];
    const int row = tid >> 4, col4 = (tid & 15) * 4;
    const int sB = tid & 15, tq = tid >> 4;
    const int ci = tid & 15, tw = tid >> 4;   // reduce-phase roles
    const float* dRow = dT  + ((size_t)b*INR + ch0 + row)*SEQL + tbase;
    const float* uRow = uct + ((size_t)b*INR + ch0 + row)*SEQL + tbase;

    for (int t0 = 0; t0 < LCH; t0 += 64) {
        __syncthreads();
        *(float4*)&dS[row][col4] = *(const float4*)&dRow[t0 + col4];
        *(float4*)&uS[row][col4] = *(const float4*)&uRow[t0 + col4];
        #pragma unroll
        for (int k = 0; k < 4; ++k)
            bT[sB][tq*4 + k] = Bm[(mb + tbase + t0 + tq*4 + k)*16 + sB];
        if (tid < 64) cS[tid] = Cv[mb + tbase + t0 + tid];
        __syncthreads();
        #pragma unroll
        for (int sub = 0; sub < 4; ++sub) {
            #pragma unroll
            for (int q = 0; q < 4; ++q) {
                float4 d4 = *(const float4*)&dS[g][sub*16 + q*4];
                float4 u4 = *(const float4*)&uS[g][sub*16 + q*4];
                float4 b4 = *(const float4*)&bT[s][sub*16 + q*4];
                h = fmaf(h, __expf(d4.x*A), u4.x*b4.x);
                hS[(q*4+0)*272 + g*17 + s] = h;
                h = fmaf(h, __expf(d4.y*A), u4.y*b4.y);
                hS[(q*4+1)*272 + g*17 + s] = h;
                h = fmaf(h, __expf(d4.z*A), u4.z*b4.z);
                hS[(q*4+2)*272 + g*17 + s] = h;
                h = fmaf(h, __expf(d4.w*A), u4.w*b4.w);
                hS[(q*4+3)*272 + g*17 + s] = h;
            }
            __syncthreads();
            float v = 0.f;
            #pragma unroll
            for (int ss = 0; ss < 16; ++ss)
                v += hS[tw*272 + ci*17 + ss];
            const int tl = sub*16 + tw;     // tile-local token 0..63
            const size_t gi = (mb + tbase + t0 + tl)*INR + ch0 + ci;
            float pv = (v * cS[tl]) * sres[gi];
            f16 hh = (f16)pv;
            AoH[gi] = hh;
            AoL[gi] = (f16)((pv - (float)hh) * 2048.f);
            __syncthreads();
        }
    }
}

// ------------------------------------------------------------------
extern "C" void kernel_launch(void* const* d_in, const int* in_sizes, int n_in,
                              void* d_out, int out_size, void* d_ws, size_t ws_size,
                              hipStream_t stream)
{
    (void)in_sizes; (void)n_in; (void)out_size; (void)ws_size;
    const float* x     = (const float*)d_in[0];
    const float* W_in  = (const float*)d_in[1];
    const float* cw    = (const float*)d_in[2];
    const float* cb    = (const float*)d_in[3];
    const float* W_x   = (const float*)d_in[4];
    const float* W_dt  = (const float*)d_in[5];
    const float* b_dt  = (const float*)d_in[6];
    const float* W_out = (const float*)d_in[7];
    const float* A_log = (const float*)d_in[8];
    float* out = (float*)d_out;

    float* ws = (float*)d_ws;
    const size_t MI = 1024 * 1024;
    // ---- memory map (float offsets; f16 buffers sized in BYTES = 2*elems):
    // [0,8Mi)    u0 -> dT (scan input)
    // [8,16Mi)   sres; later pK split-K partials [8,12Mi)+[12,16Mi)
    // [16,24Mi)  phase1: Xhi/Xlo/Whi/Wlo; then uct; then WoH/WoL after scan3
    // [24,28Mi)  AoH (8Mi f16 = 16 MiB)   <- disjoint, checked
    // [28,32Mi)  AoL (8Mi f16 = 16 MiB)   <- ends at dtin (dead by then)
    // [32Mi,..)  dtin 64Ki | Bm 64Ki | Cv 4Ki | WxT 66Ki
    float* u0   = ws;
    float* sres = ws + 8*MI;
    float* uct  = ws + 16*MI;
    float* part = ws + 24*MI;         // ssm partials (2.06Mi, dead before AoH)
    float* dtin = ws + 32*MI;
    float* Bm   = dtin + 65536;
    float* Cv   = Bm + 65536;
    float* WxT  = Cv + 4096;
    float* dT   = u0;
    // chunk-scan aggregates live in d_out (dead until addout): 1Mi floats
    float* houtb = out;               // hout, then hin in-place
    float* Eag   = out + 524288;
    // f16 planes, phase 1 (gemm1 inputs) — over [16,24Mi), dead after gemm1
    f16* Xhi = (f16*)(ws + 16*MI);
    f16* Xlo = (f16*)(ws + 18*MI);
    f16* Whi = (f16*)(ws + 20*MI);
    f16* Wlo = (f16*)(ws + 22*MI);
    // f16 planes, phase 2 (gemmout inputs)
    f16* AoH = (f16*)(ws + 24*MI);    // bytes [96,112 MiB)
    f16* AoL = (f16*)(ws + 28*MI);    // bytes [112,128 MiB)
    f16* WoH = (f16*)(ws + 16*MI);    // dead-uct region, written after scan3
    f16* WoL = (f16*)(ws + 17*MI);
    float* pK = sres;                 // split-K partials

    k_prep     <<<dim3(264 + 2048 + 2048), 256, 0, stream>>>(
                    W_x, WxT, x, Xhi, Xlo, W_in, Whi, Wlo);
    k_gemm_split<<<dim3(64, 32, 1), 256, 0, stream>>>(Xhi, Xlo, Whi, Wlo,
                    DIMM, DIMM, 1, INR, u0, sres);
    k_conv     <<<dim3(32, 32, 2), 256, 0, stream>>>(u0, cw, cb, uct);
    k_ssm_part <<<dim3(8, 16, 2), 256, 0, stream>>>(uct, WxT, part);
    k_ssm_reduce<<<dim3((33*TOKS + 255)/256), 256, 0, stream>>>(part, dtin, Bm, Cv);
    k_delta    <<<dim3(32, 64), 256, 0, stream>>>(dtin, W_dt, b_dt, dT);
    k_scan1    <<<dim3(128, NCH, 2), 256, 0, stream>>>(dT, uct, Bm, A_log, houtb, Eag);
    k_scan2    <<<dim3(256), 256, 0, stream>>>(houtb, Eag, houtb);
    k_scan3    <<<dim3(128, NCH, 2), 256, 0, stream>>>(dT, uct, Bm, Cv, A_log,
                    houtb, sres, AoH, AoL);
    k_cvt_pair <<<dim3(1024), 256, 0, stream>>>(W_out, WoH, WoL, 262144);
    k_gemm_split<<<dim3(16, 32, 2), 256, 0, stream>>>(AoH, AoL, WoH, WoL,
                    DIMM, INR, 0, DIMM, pK, nullptr);
    k_addout   <<<dim3(4096), 256, 0, stream>>>(pK, out);
}